// Round 3
// baseline (312.991 us; speedup 1.0000x reference)
//
#include <hip/hip_runtime.h>
#include <stdint.h>

// Spread 8 bits of a byte into 8 byte-lanes of a uint64.
// Lane k (byte k) gets bit (7-k) of b, as 0 or 1.
__device__ __forceinline__ uint64_t spread8(uint32_t b) {
    return (((uint64_t)b * 0x8040201008040201ULL) >> 7) & 0x0101010101010101ULL;
}

// Kernel 1: per byte-position bit counts over all votes.
// One thread per byte position -> 8192 waves (32 waves/CU, max occupancy).
// Vote loop in batches of 8 independent loads for ILP. No atomics on cnt.
__global__ __launch_bounds__(256) void k_count(const int* __restrict__ flip,
                                               uint64_t* __restrict__ cnt,
                                               unsigned int* __restrict__ total,
                                               int npos, int nvotes) {
    int t = blockIdx.x * blockDim.x + threadIdx.x;   // byte position
    if (t >= npos) return;
    uint64_t c = 0;
    unsigned int pop = 0;
    int v = 0;
    for (; v + 8 <= nvotes; v += 8) {
        int xs[8];
#pragma unroll
        for (int j = 0; j < 8; ++j)
            xs[j] = flip[(size_t)(v + j) * npos + t];
#pragma unroll
        for (int j = 0; j < 8; ++j) {
            uint32_t b = (uint32_t)xs[j] & 0xFFu;
            c += spread8(b);
            pop += __popc(b);
        }
    }
    for (; v < nvotes; ++v) {                 // tail (unused for nvotes=32)
        uint32_t b = (uint32_t)flip[(size_t)v * npos + t] & 0xFFu;
        c += spread8(b);
        pop += __popc(b);
    }
    cnt[t] = c;                               // coalesced 8B store
    for (int off = 32; off > 0; off >>= 1)
        pop += __shfl_down(pop, off, 64);
    if ((threadIdx.x & 63) == 0)
        atomicAdd(total, pop);
}

// Kernel 2: threshold, build mask, XNOR with weights, write floats, count mask
// bits; last block writes the update ratio.
__global__ __launch_bounds__(256) void k_apply(const int* __restrict__ weights,
                                               const uint64_t* __restrict__ cnt,
                                               const unsigned int* __restrict__ total,
                                               const float* __restrict__ vote_p_max,
                                               const int* __restrict__ n_votes_p,
                                               float* __restrict__ out,
                                               unsigned int* __restrict__ maskpop,
                                               unsigned int* __restrict__ done,
                                               int npos) {
    int t = blockIdx.x * blockDim.x + threadIdx.x;   // byte position
    if (t < npos) {
        float nv = (float)n_votes_p[0];
        float mean = (float)((double)(*total) / ((double)npos * 8.0));
        float thresh = fmaxf(vote_p_max[0] * nv, mean);  // == max(p,mean/nv)*nv
        uint64_t c = cnt[t];
        uint32_t w = (uint32_t)weights[t];
        uint32_t mask = 0;
#pragma unroll
        for (int k = 0; k < 8; ++k) {
            uint32_t lane = (uint32_t)(c >> (8 * k)) & 0xFFu;  // count of bit 7-k
            if ((float)lane > thresh) mask |= 1u << (7 - k);
        }
        out[t] = (float)((~(w ^ mask)) & 0xFFu);
        unsigned int pop = __popc(mask);
        for (int off = 32; off > 0; off >>= 1)
            pop += __shfl_down(pop, off, 64);
        if ((threadIdx.x & 63) == 0)
            atomicAdd(maskpop, pop);
    }
    __syncthreads();
    __shared__ bool last;
    if (threadIdx.x == 0) {
        __threadfence();
        unsigned int prev = atomicAdd(done, 1);
        last = (prev == gridDim.x - 1);
    }
    __syncthreads();
    if (last && threadIdx.x == 0) {
        unsigned int mp = atomicAdd(maskpop, 0u);    // coherent read after all adds
        out[npos] = (float)((double)mp / ((double)npos * 8.0));
    }
}

extern "C" void kernel_launch(void* const* d_in, const int* in_sizes, int n_in,
                              void* d_out, int out_size, void* d_ws, size_t ws_size,
                              hipStream_t stream) {
    const int* weights      = (const int*)d_in[0];   // 2048*256 bytes, one per int32
    const int* flip         = (const int*)d_in[1];   // 32*2048*256, one byte per int32
    const int* n_votes_p    = (const int*)d_in[2];
    const float* vote_p_max = (const float*)d_in[3];

    int npos   = in_sizes[0];               // 524288 byte positions
    int nvotes = in_sizes[1] / in_sizes[0]; // 32

    // ws layout: [0..256) counters (total, maskpop, done); [256..256+8*npos) counts
    unsigned int* counters = (unsigned int*)d_ws;
    uint64_t* cnt = (uint64_t*)((char*)d_ws + 256);
    hipMemsetAsync(d_ws, 0, 256, stream);   // zero the three counters only

    int block = 256;
    int grid = (npos + block - 1) / block;  // 2048

    k_count<<<grid, block, 0, stream>>>(flip, cnt, counters, npos, nvotes);
    k_apply<<<grid, block, 0, stream>>>(weights, cnt, counters, vote_p_max,
                                        n_votes_p, (float*)d_out, counters + 1,
                                        counters + 2, npos);
}

// Round 4
// 285.311 us; speedup vs baseline: 1.0970x; 1.0970x over previous
//
#include <hip/hip_runtime.h>
#include <stdint.h>

// Spread 8 bits of a byte into 8 byte-lanes of a uint64.
// Lane k (byte k) gets bit (7-k) of b, as 0 or 1.
__device__ __forceinline__ uint64_t spread8(uint32_t b) {
    return (((uint64_t)b * 0x8040201008040201ULL) >> 7) & 0x0101010101010101ULL;
}

// Kernel 1: per byte-position bit counts over all votes.
// One thread per byte position -> 8192 waves (32 waves/CU).
// Vote loop in batches of 16 independent loads for deep MLP. No atomics on cnt.
__global__ __launch_bounds__(256) void k_count(const int* __restrict__ flip,
                                               uint64_t* __restrict__ cnt,
                                               unsigned int* __restrict__ total,
                                               int npos, int nvotes) {
    int t = blockIdx.x * blockDim.x + threadIdx.x;   // byte position
    if (t >= npos) return;
    uint64_t c = 0;
    unsigned int pop = 0;
    int v = 0;
    for (; v + 16 <= nvotes; v += 16) {
        int xs[16];
#pragma unroll
        for (int j = 0; j < 16; ++j)
            xs[j] = flip[(size_t)(v + j) * npos + t];
#pragma unroll
        for (int j = 0; j < 16; ++j) {
            uint32_t b = (uint32_t)xs[j] & 0xFFu;
            c += spread8(b);
            pop += __popc(b);
        }
    }
    for (; v < nvotes; ++v) {                 // tail (unused for nvotes=32)
        uint32_t b = (uint32_t)flip[(size_t)v * npos + t] & 0xFFu;
        c += spread8(b);
        pop += __popc(b);
    }
    cnt[t] = c;                               // coalesced 8B store
    for (int off = 32; off > 0; off >>= 1)
        pop += __shfl_down(pop, off, 64);
    if ((threadIdx.x & 63) == 0)
        atomicAdd(total, pop);                // device-coherent, no fence needed
}

// Kernel 2: threshold, build mask, XNOR with weights, write floats, count mask
// bits. NO fences, NO last-block pattern (device-scope fences force per-block
// L2 writebacks on CDNA chiplets -> 125us stall in R3).
__global__ __launch_bounds__(256) void k_apply(const int* __restrict__ weights,
                                               const uint64_t* __restrict__ cnt,
                                               const unsigned int* __restrict__ total,
                                               const float* __restrict__ vote_p_max,
                                               const int* __restrict__ n_votes_p,
                                               float* __restrict__ out,
                                               unsigned int* __restrict__ maskpop,
                                               int npos) {
    int t = blockIdx.x * blockDim.x + threadIdx.x;   // byte position
    if (t >= npos) return;
    float nv = (float)n_votes_p[0];
    float mean = (float)((double)(*total) / ((double)npos * 8.0));
    float thresh = fmaxf(vote_p_max[0] * nv, mean);  // == max(p,mean/nv)*nv
    uint64_t c = cnt[t];
    uint32_t w = (uint32_t)weights[t];
    uint32_t mask = 0;
#pragma unroll
    for (int k = 0; k < 8; ++k) {
        uint32_t lane = (uint32_t)(c >> (8 * k)) & 0xFFu;  // count of bit 7-k
        if ((float)lane > thresh) mask |= 1u << (7 - k);
    }
    out[t] = (float)((~(w ^ mask)) & 0xFFu);
    unsigned int pop = __popc(mask);
    for (int off = 32; off > 0; off >>= 1)
        pop += __shfl_down(pop, off, 64);
    if ((threadIdx.x & 63) == 0)
        atomicAdd(maskpop, pop);              // device-coherent, no fence needed
}

// Kernel 3: one thread writes the update ratio. Kernel boundary gives
// visibility of maskpop — no fences anywhere.
__global__ void k_ratio(const unsigned int* __restrict__ maskpop,
                        float* __restrict__ out, int npos) {
    out[npos] = (float)((double)(*maskpop) / ((double)npos * 8.0));
}

extern "C" void kernel_launch(void* const* d_in, const int* in_sizes, int n_in,
                              void* d_out, int out_size, void* d_ws, size_t ws_size,
                              hipStream_t stream) {
    const int* weights      = (const int*)d_in[0];   // 2048*256 bytes, one per int32
    const int* flip         = (const int*)d_in[1];   // 32*2048*256, one byte per int32
    const int* n_votes_p    = (const int*)d_in[2];
    const float* vote_p_max = (const float*)d_in[3];

    int npos   = in_sizes[0];               // 524288 byte positions
    int nvotes = in_sizes[1] / in_sizes[0]; // 32

    // ws layout: [0..256) counters (total, maskpop); [256..256+8*npos) counts
    unsigned int* counters = (unsigned int*)d_ws;
    uint64_t* cnt = (uint64_t*)((char*)d_ws + 256);
    hipMemsetAsync(d_ws, 0, 256, stream);   // zero the two counters only

    int block = 256;
    int grid = (npos + block - 1) / block;  // 2048

    k_count<<<grid, block, 0, stream>>>(flip, cnt, counters, npos, nvotes);
    k_apply<<<grid, block, 0, stream>>>(weights, cnt, counters, vote_p_max,
                                        n_votes_p, (float*)d_out, counters + 1, npos);
    k_ratio<<<1, 1, 0, stream>>>(counters + 1, (float*)d_out, npos);
}

// Round 5
// 149.168 us; speedup vs baseline: 2.0982x; 1.9127x over previous
//
#include <hip/hip_runtime.h>
#include <stdint.h>

// Spread 8 bits of a byte into 8 byte-lanes of a uint64.
// Lane k (byte k) gets bit (7-k) of b, as 0 or 1.
__device__ __forceinline__ uint64_t spread8(uint32_t b) {
    return (((uint64_t)b * 0x8040201008040201ULL) >> 7) & 0x0101010101010101ULL;
}

// Sum of the 8 byte lanes (valid while sum < 256).
__device__ __forceinline__ uint32_t bytesum(uint64_t c) {
    return (uint32_t)((c * 0x0101010101010101ULL) >> 56);
}

// Kernel 1: partial per byte-position bit counts over one vote chunk.
// blockIdx.y = chunk. Each thread owns 4 consecutive byte positions (int4
// loads, 16B/lane) and its own slot in `partial` — NO atomics, NO fences.
// 8 int4 loads kept in flight per batch (~32 data VGPRs).
__global__ __launch_bounds__(256) void k_count(const int* __restrict__ flip,
                                               uint64_t* __restrict__ partial,
                                               unsigned int* __restrict__ total,
                                               int npos, int nvotes, int vchunk) {
    int t = blockIdx.x * blockDim.x + threadIdx.x;   // position-group id
    int base = t * 4;
    if (base >= npos) return;
    int v0 = blockIdx.y * vchunk;
    int v1 = v0 + vchunk; if (v1 > nvotes) v1 = nvotes;
    int stride = npos >> 2;                          // int4 stride between votes
    const int4* fp = (const int4*)flip + (size_t)v0 * stride + t;
    uint64_t c0 = 0, c1 = 0, c2 = 0, c3 = 0;
    int v = v0;
    for (; v + 8 <= v1; v += 8) {
        int4 x[8];
#pragma unroll
        for (int j = 0; j < 8; ++j)
            x[j] = fp[(size_t)j * stride];
        fp += (size_t)8 * stride;
#pragma unroll
        for (int j = 0; j < 8; ++j) {
            c0 += spread8((uint32_t)x[j].x & 0xFFu);
            c1 += spread8((uint32_t)x[j].y & 0xFFu);
            c2 += spread8((uint32_t)x[j].z & 0xFFu);
            c3 += spread8((uint32_t)x[j].w & 0xFFu);
        }
    }
    for (; v < v1; ++v) {                            // tail
        int4 x = *fp; fp += stride;
        c0 += spread8((uint32_t)x.x & 0xFFu);
        c1 += spread8((uint32_t)x.y & 0xFFu);
        c2 += spread8((uint32_t)x.z & 0xFFu);
        c3 += spread8((uint32_t)x.w & 0xFFu);
    }
    uint64_t* p = partial + (size_t)blockIdx.y * npos + base;
    ((ulonglong2*)p)[0] = make_ulonglong2(c0, c1);
    ((ulonglong2*)p)[1] = make_ulonglong2(c2, c3);
    // chunk popcount = sum of byte lanes (lanes <= 8, bytesum <= 64)
    unsigned int pop = bytesum(c0) + bytesum(c1) + bytesum(c2) + bytesum(c3);
    for (int off = 32; off > 0; off >>= 1)
        pop += __shfl_down(pop, off, 64);
    __shared__ unsigned int sred[4];
    int wid = threadIdx.x >> 6;
    if ((threadIdx.x & 63) == 0) sred[wid] = pop;
    __syncthreads();
    if (threadIdx.x == 0)
        atomicAdd(total, sred[0] + sred[1] + sred[2] + sred[3]);  // 1 atomic/block
}

// Kernel 2: sum partials, threshold, build mask, XNOR, write floats,
// accumulate mask popcount (1 atomic/block). No fences.
__global__ __launch_bounds__(256) void k_apply(const int* __restrict__ weights,
                                               const uint64_t* __restrict__ partial,
                                               const unsigned int* __restrict__ total,
                                               const float* __restrict__ vote_p_max,
                                               const int* __restrict__ n_votes_p,
                                               float* __restrict__ out,
                                               unsigned int* __restrict__ maskpop,
                                               int npos, int nch) {
    int t = blockIdx.x * blockDim.x + threadIdx.x;   // byte position
    unsigned int pop = 0;
    if (t < npos) {
        float nv = (float)n_votes_p[0];
        float mean = (float)((double)(*total) / ((double)npos * 8.0));
        float thresh = fmaxf(vote_p_max[0] * nv, mean);  // == max(p,mean/nv)*nv
        uint64_t c = 0;
        if (nch == 4) {
            c = partial[t] + partial[(size_t)npos + t]
              + partial[(size_t)2 * npos + t] + partial[(size_t)3 * npos + t];
        } else {
            for (int ch = 0; ch < nch; ++ch)
                c += partial[(size_t)ch * npos + t];
        }
        uint32_t w = (uint32_t)weights[t];
        uint32_t mask = 0;
#pragma unroll
        for (int k = 0; k < 8; ++k) {
            uint32_t lane = (uint32_t)(c >> (8 * k)) & 0xFFu;  // count of bit 7-k
            if ((float)lane > thresh) mask |= 1u << (7 - k);
        }
        out[t] = (float)((~(w ^ mask)) & 0xFFu);
        pop = __popc(mask);
    }
    for (int off = 32; off > 0; off >>= 1)
        pop += __shfl_down(pop, off, 64);
    __shared__ unsigned int sred[4];
    int wid = threadIdx.x >> 6;
    if ((threadIdx.x & 63) == 0) sred[wid] = pop;
    __syncthreads();
    if (threadIdx.x == 0)
        atomicAdd(maskpop, sred[0] + sred[1] + sred[2] + sred[3]);
}

// Kernel 3: write the update ratio (kernel boundary = ordering, no fences).
__global__ void k_ratio(const unsigned int* __restrict__ maskpop,
                        float* __restrict__ out, int npos) {
    out[npos] = (float)((double)(*maskpop) / ((double)npos * 8.0));
}

extern "C" void kernel_launch(void* const* d_in, const int* in_sizes, int n_in,
                              void* d_out, int out_size, void* d_ws, size_t ws_size,
                              hipStream_t stream) {
    const int* weights      = (const int*)d_in[0];   // 2048*256 bytes, one per int32
    const int* flip         = (const int*)d_in[1];   // 32*2048*256, one byte per int32
    const int* n_votes_p    = (const int*)d_in[2];
    const float* vote_p_max = (const float*)d_in[3];

    int npos   = in_sizes[0];               // 524288 byte positions
    int nvotes = in_sizes[1] / in_sizes[0]; // 32

    // ws layout: [0..256) counters (total, maskpop); [256..) partial counts
    unsigned int* counters = (unsigned int*)d_ws;
    uint64_t* partial = (uint64_t*)((char*)d_ws + 256);

    // pick vote-chunk count by available scratch (4 needs 16 MB)
    size_t slots = ws_size > 256 ? (ws_size - 256) / ((size_t)npos * 8) : 1;
    int nch = slots >= 4 ? 4 : (slots >= 2 ? 2 : 1);
    int vchunk = (nvotes + nch - 1) / nch;

    hipMemsetAsync(d_ws, 0, 256, stream);   // zero the two counters only

    int block = 256;
    int gx = (npos / 4 + block - 1) / block;          // 512
    dim3 gridc(gx, nch);
    k_count<<<gridc, block, 0, stream>>>(flip, partial, counters, npos, nvotes, vchunk);

    int ga = (npos + block - 1) / block;              // 2048
    k_apply<<<ga, block, 0, stream>>>(weights, partial, counters, vote_p_max,
                                      n_votes_p, (float*)d_out, counters + 1,
                                      npos, nch);
    k_ratio<<<1, 1, 0, stream>>>(counters + 1, (float*)d_out, npos);
}

// Round 6
// 131.554 us; speedup vs baseline: 2.3792x; 1.1339x over previous
//
#include <hip/hip_runtime.h>
#include <stdint.h>

typedef unsigned int u32;

// bit-sliced full adder: s = a^b^cin, cout = majority(a,b,cin), per bit position
__device__ __forceinline__ void fadd(u32 a, u32 b, u32 cin, u32& s, u32& cout) {
    u32 axb = a ^ b;
    s = axb ^ cin;
    cout = (a & b) | (cin & axb);
}

// Kernel 1: bit-sliced partial counts over one vote chunk (<= 8 votes).
// Thread owns 4 byte positions packed into u32 bit lanes; counts kept as 4
// bitplanes (values <= 8). Partial slot per (chunk, thread): int4 = 16 B.
// No atomics on partials, no fences. blockIdx.y = vote chunk.
__global__ __launch_bounds__(256) void k_count(const int* __restrict__ flip,
                                               int4* __restrict__ partial,
                                               u32* __restrict__ total,
                                               int npos, int nvotes, int vchunk) {
    int t = blockIdx.x * blockDim.x + threadIdx.x;   // position-group id
    int pgs = npos >> 2;                             // groups of 4 positions
    u32 pop = 0;
    if (t < pgs) {
        int v0 = blockIdx.y * vchunk;
        int n = nvotes - v0; if (n > vchunk) n = vchunk;   // wave-uniform
        const int4* fp = (const int4*)flip + (size_t)v0 * pgs + t;
        int4 x[8];
#pragma unroll
        for (int j = 0; j < 8; ++j)
            if (j < n) x[j] = fp[(size_t)j * pgs];   // 8 coalesced 16B loads in flight
        u32 p0 = 0, p1 = 0, p2 = 0, p3 = 0;          // bitplanes of per-bit counts
#pragma unroll
        for (int j = 0; j < 8; ++j) {
            if (j < n) {
                u32 w = ((u32)x[j].x & 0xFFu) | (((u32)x[j].y & 0xFFu) << 8)
                      | (((u32)x[j].z & 0xFFu) << 16) | (((u32)x[j].w & 0xFFu) << 24);
                pop += __popc(w);
                u32 c = w, tn;
                tn = p0 & c; p0 ^= c; c = tn;        // ripple-carry add of 1 bit
                tn = p1 & c; p1 ^= c; c = tn;
                tn = p2 & c; p2 ^= c; c = tn;
                p3 ^= c;                             // count <= 8 fits bit 3
            }
        }
        partial[(size_t)blockIdx.y * pgs + t] =
            make_int4((int)p0, (int)p1, (int)p2, (int)p3);  // coalesced 16B store
    }
    for (int off = 32; off > 0; off >>= 1)
        pop += __shfl_down(pop, off, 64);
    __shared__ u32 sred[4];
    int wid = threadIdx.x >> 6;
    if ((threadIdx.x & 63) == 0) sred[wid] = pop;
    __syncthreads();
    if (threadIdx.x == 0)
        atomicAdd(total, sred[0] + sred[1] + sred[2] + sred[3]);  // 1 atomic/block
}

// Kernel 2: sum chunk bitplanes (bit-sliced adders), threshold compare done
// bitwise across all 32 positions at once, XNOR with weights, write float4,
// accumulate mask popcount. No fences (R3 lesson).
__global__ __launch_bounds__(256) void k_apply(const int* __restrict__ weights,
                                               const int4* __restrict__ partial,
                                               const u32* __restrict__ total,
                                               const float* __restrict__ vote_p_max,
                                               const int* __restrict__ n_votes_p,
                                               float* __restrict__ out,
                                               u32* __restrict__ maskpop,
                                               int npos, int nch) {
    int t = blockIdx.x * blockDim.x + threadIdx.x;   // position-group id
    int pgs = npos >> 2;
    u32 pop = 0;
    if (t < pgs) {
        float nv = (float)n_votes_p[0];
        float mean = (float)((double)(*total) / ((double)npos * 8.0));
        float thresh = fmaxf(vote_p_max[0] * nv, mean);  // == max(p,mean/nv)*nv (nv=2^k)
        int K = (int)floorf(thresh) + 1;   // integer count > thresh  <=>  count >= K
        if (K < 0) K = 0;
        if (K > 64) K = 64;
        u32 Kp = (u32)(64 - K);            // carry-out of (count + Kp) <=> count >= K
        // 6-plane bit-sliced accumulator (total count <= 32)
        u32 a0 = 0, a1 = 0, a2 = 0, a3 = 0, a4 = 0, a5 = 0;
        for (int ch = 0; ch < nch; ++ch) {
            int4 q = partial[(size_t)ch * pgs + t];
            u32 car;
            fadd(a0, (u32)q.x, 0u, a0, car);
            fadd(a1, (u32)q.y, car, a1, car);
            fadd(a2, (u32)q.z, car, a2, car);
            fadd(a3, (u32)q.w, car, a3, car);
            u32 c5 = a4 & car; a4 ^= car; a5 ^= c5;
        }
        // ripple carry of (count + Kp): K is wave-uniform, 1 op/plane
        u32 carry = (Kp & 1u)  ? a0 : 0u;
        carry = (Kp & 2u)  ? (a1 | carry) : (a1 & carry);
        carry = (Kp & 4u)  ? (a2 | carry) : (a2 & carry);
        carry = (Kp & 8u)  ? (a3 | carry) : (a3 & carry);
        carry = (Kp & 16u) ? (a4 | carry) : (a4 & carry);
        carry = (Kp & 32u) ? (a5 | carry) : (a5 & carry);
        u32 mask = (K == 0) ? 0xFFFFFFFFu : carry;
        int4 wv = ((const int4*)weights)[t];
        u32 ww = ((u32)wv.x & 0xFFu) | (((u32)wv.y & 0xFFu) << 8)
               | (((u32)wv.z & 0xFFu) << 16) | (((u32)wv.w & 0xFFu) << 24);
        u32 xn = ~(ww ^ mask);
        ((float4*)out)[t] = make_float4((float)(xn & 0xFFu),
                                        (float)((xn >> 8) & 0xFFu),
                                        (float)((xn >> 16) & 0xFFu),
                                        (float)((xn >> 24) & 0xFFu));
        pop = __popc(mask);
    }
    for (int off = 32; off > 0; off >>= 1)
        pop += __shfl_down(pop, off, 64);
    __shared__ u32 sred[4];
    int wid = threadIdx.x >> 6;
    if ((threadIdx.x & 63) == 0) sred[wid] = pop;
    __syncthreads();
    if (threadIdx.x == 0)
        atomicAdd(maskpop, sred[0] + sred[1] + sred[2] + sred[3]);
}

// Kernel 3: write the update ratio (kernel boundary = ordering, no fences).
__global__ void k_ratio(const u32* __restrict__ maskpop,
                        float* __restrict__ out, int npos) {
    out[npos] = (float)((double)(*maskpop) / ((double)npos * 8.0));
}

extern "C" void kernel_launch(void* const* d_in, const int* in_sizes, int n_in,
                              void* d_out, int out_size, void* d_ws, size_t ws_size,
                              hipStream_t stream) {
    const int* weights      = (const int*)d_in[0];   // 2048*256 bytes, one per int32
    const int* flip         = (const int*)d_in[1];   // 32*2048*256, one byte per int32
    const int* n_votes_p    = (const int*)d_in[2];
    const float* vote_p_max = (const float*)d_in[3];

    int npos   = in_sizes[0];               // 524288 byte positions
    int nvotes = in_sizes[1] / in_sizes[0]; // 32
    int pgs    = npos / 4;                  // 131072 position groups

    // chunks of <= 8 votes so chunk counts fit 4 bitplanes
    int nch = (nvotes + 7) / 8;             // 4
    int vchunk = 8;

    // ws layout: [0..256) counters (total, maskpop); [256..) bitplane partials
    unsigned int* counters = (unsigned int*)d_ws;
    int4* partial = (int4*)((char*)d_ws + 256);      // nch * pgs * 16 B = 8 MB
    hipMemsetAsync(d_ws, 0, 256, stream);   // zero the two counters only

    int block = 256;
    int gx = (pgs + block - 1) / block;     // 512

    dim3 gridc(gx, nch);
    k_count<<<gridc, block, 0, stream>>>(flip, partial, counters, npos, nvotes, vchunk);
    k_apply<<<gx, block, 0, stream>>>(weights, partial, counters, vote_p_max,
                                      n_votes_p, (float*)d_out, counters + 1,
                                      npos, nch);
    k_ratio<<<1, 1, 0, stream>>>(counters + 1, (float*)d_out, npos);
}

// Round 7
// 106.880 us; speedup vs baseline: 2.9284x; 1.2309x over previous
//
#include <hip/hip_runtime.h>
#include <stdint.h>

typedef unsigned int u32;

// Kernel 1: single-pass bit-sliced vote counts.
// One thread per 4 byte-positions (= 32 bit-positions packed in u32 lanes).
// All 32 votes accumulated into a 6-plane bit-sliced counter (count <= 32).
// 8 int4 loads kept in flight (the R1/R4 latency fix); no partial chunks,
// no atomics, no fences, no memset. Per-block popcount -> plain slot.
__global__ __launch_bounds__(256) void k_count(const int* __restrict__ flip,
                                               u32* __restrict__ planes,
                                               u32* __restrict__ popslot,
                                               int npos, int nvotes) {
    int t = blockIdx.x * blockDim.x + threadIdx.x;   // position-group id
    int pgs = npos >> 2;
    u32 pop = 0;
    if (t < pgs) {
        const int4* fp = (const int4*)flip + t;
        u32 p0 = 0, p1 = 0, p2 = 0, p3 = 0, p4 = 0, p5 = 0;
        int v = 0;
        for (; v + 8 <= nvotes; v += 8) {
            int4 x[8];
#pragma unroll
            for (int j = 0; j < 8; ++j)
                x[j] = fp[(size_t)(v + j) * pgs];    // 8 coalesced 16B loads in flight
#pragma unroll
            for (int j = 0; j < 8; ++j) {
                u32 w = ((u32)x[j].x & 0xFFu) | (((u32)x[j].y & 0xFFu) << 8)
                      | (((u32)x[j].z & 0xFFu) << 16) | (((u32)x[j].w & 0xFFu) << 24);
                pop += __popc(w);
                u32 c = w, tn;                       // ripple +1 through 6 planes
                tn = p0 & c; p0 ^= c; c = tn;
                tn = p1 & c; p1 ^= c; c = tn;
                tn = p2 & c; p2 ^= c; c = tn;
                tn = p3 & c; p3 ^= c; c = tn;
                tn = p4 & c; p4 ^= c; c = tn;
                p5 ^= c;
            }
        }
        for (; v < nvotes; ++v) {                    // tail (unused for nvotes=32)
            int4 x = fp[(size_t)v * pgs];
            u32 w = ((u32)x.x & 0xFFu) | (((u32)x.y & 0xFFu) << 8)
                  | (((u32)x.z & 0xFFu) << 16) | (((u32)x.w & 0xFFu) << 24);
            pop += __popc(w);
            u32 c = w, tn;
            tn = p0 & c; p0 ^= c; c = tn;
            tn = p1 & c; p1 ^= c; c = tn;
            tn = p2 & c; p2 ^= c; c = tn;
            tn = p3 & c; p3 ^= c; c = tn;
            tn = p4 & c; p4 ^= c; c = tn;
            p5 ^= c;
        }
        planes[t]                   = p0;            // SoA: 6 coalesced 4B stores
        planes[(size_t)pgs + t]     = p1;
        planes[(size_t)2*pgs + t]   = p2;
        planes[(size_t)3*pgs + t]   = p3;
        planes[(size_t)4*pgs + t]   = p4;
        planes[(size_t)5*pgs + t]   = p5;
    }
    for (int off = 32; off > 0; off >>= 1)
        pop += __shfl_down(pop, off, 64);
    __shared__ u32 sred[4];
    int wid = threadIdx.x >> 6;
    if ((threadIdx.x & 63) == 0) sred[wid] = pop;
    __syncthreads();
    if (threadIdx.x == 0)
        popslot[blockIdx.x] = sred[0] + sred[1] + sred[2] + sred[3];  // no atomic
}

// Kernel 2: each block redundantly sums the 512 popslots (L2-hit, 2KB) to get
// the threshold, then bitwise threshold compare across 32 positions at once,
// XNOR with weights, float4 store, per-block mask popcount -> plain slot.
__global__ __launch_bounds__(256) void k_apply(const int* __restrict__ weights,
                                               const u32* __restrict__ planes,
                                               const u32* __restrict__ popslot,
                                               const float* __restrict__ vote_p_max,
                                               const int* __restrict__ n_votes_p,
                                               float* __restrict__ out,
                                               u32* __restrict__ maskslot,
                                               int npos, int nblk) {
    int pgs = npos >> 2;
    __shared__ u32 sred[4];
    __shared__ float s_thresh;
    // block-redundant total: sum popslot[0..nblk)
    u32 s = 0;
    for (int i = threadIdx.x; i < nblk; i += blockDim.x) s += popslot[i];
    for (int off = 32; off > 0; off >>= 1) s += __shfl_down(s, off, 64);
    int wid = threadIdx.x >> 6;
    if ((threadIdx.x & 63) == 0) sred[wid] = s;
    __syncthreads();
    if (threadIdx.x == 0) {
        u32 total = sred[0] + sred[1] + sred[2] + sred[3];
        float nv = (float)n_votes_p[0];
        float mean = (float)((double)total / ((double)npos * 8.0));
        s_thresh = fmaxf(vote_p_max[0] * nv, mean);  // == max(p,mean/nv)*nv
    }
    __syncthreads();
    float thresh = s_thresh;
    int t = blockIdx.x * blockDim.x + threadIdx.x;
    u32 pop = 0;
    if (t < pgs) {
        int K = (int)floorf(thresh) + 1;   // count > thresh  <=>  count >= K
        if (K < 0) K = 0;
        if (K > 64) K = 64;
        u32 Kp = (u32)(64 - K);            // carry-out of (count + Kp) <=> count >= K
        u32 a0 = planes[t];
        u32 a1 = planes[(size_t)pgs + t];
        u32 a2 = planes[(size_t)2*pgs + t];
        u32 a3 = planes[(size_t)3*pgs + t];
        u32 a4 = planes[(size_t)4*pgs + t];
        u32 a5 = planes[(size_t)5*pgs + t];
        u32 carry = (Kp & 1u)  ? a0 : 0u;  // ripple carry, K wave-uniform
        carry = (Kp & 2u)  ? (a1 | carry) : (a1 & carry);
        carry = (Kp & 4u)  ? (a2 | carry) : (a2 & carry);
        carry = (Kp & 8u)  ? (a3 | carry) : (a3 & carry);
        carry = (Kp & 16u) ? (a4 | carry) : (a4 & carry);
        carry = (Kp & 32u) ? (a5 | carry) : (a5 & carry);
        u32 mask = (K == 0) ? 0xFFFFFFFFu : carry;
        int4 wv = ((const int4*)weights)[t];
        u32 ww = ((u32)wv.x & 0xFFu) | (((u32)wv.y & 0xFFu) << 8)
               | (((u32)wv.z & 0xFFu) << 16) | (((u32)wv.w & 0xFFu) << 24);
        u32 xn = ~(ww ^ mask);
        ((float4*)out)[t] = make_float4((float)(xn & 0xFFu),
                                        (float)((xn >> 8) & 0xFFu),
                                        (float)((xn >> 16) & 0xFFu),
                                        (float)((xn >> 24) & 0xFFu));
        pop = __popc(mask);
    }
    for (int off = 32; off > 0; off >>= 1)
        pop += __shfl_down(pop, off, 64);
    __syncthreads();                        // sred reuse
    if ((threadIdx.x & 63) == 0) sred[wid] = pop;
    __syncthreads();
    if (threadIdx.x == 0)
        maskslot[blockIdx.x] = sred[0] + sred[1] + sred[2] + sred[3];
}

// Kernel 3: sum mask-pop slots, write update ratio. Kernel boundary = ordering.
__global__ __launch_bounds__(256) void k_ratio(const u32* __restrict__ maskslot,
                                               float* __restrict__ out,
                                               int npos, int nblk) {
    __shared__ u32 sred[4];
    u32 s = 0;
    for (int i = threadIdx.x; i < nblk; i += blockDim.x) s += maskslot[i];
    for (int off = 32; off > 0; off >>= 1) s += __shfl_down(s, off, 64);
    int wid = threadIdx.x >> 6;
    if ((threadIdx.x & 63) == 0) sred[wid] = s;
    __syncthreads();
    if (threadIdx.x == 0) {
        u32 mp = sred[0] + sred[1] + sred[2] + sred[3];
        out[npos] = (float)((double)mp / ((double)npos * 8.0));
    }
}

extern "C" void kernel_launch(void* const* d_in, const int* in_sizes, int n_in,
                              void* d_out, int out_size, void* d_ws, size_t ws_size,
                              hipStream_t stream) {
    const int* weights      = (const int*)d_in[0];   // 2048*256 bytes, one per int32
    const int* flip         = (const int*)d_in[1];   // 32*2048*256, one byte per int32
    const int* n_votes_p    = (const int*)d_in[2];
    const float* vote_p_max = (const float*)d_in[3];

    int npos   = in_sizes[0];               // 524288 byte positions
    int nvotes = in_sizes[1] / in_sizes[0]; // 32
    int pgs    = npos / 4;                  // 131072 position groups

    int block = 256;
    int gx = (pgs + block - 1) / block;     // 512 blocks

    // ws layout (no memset needed — all slots fully written before read):
    // [0 .. 4*gx)            popslot
    // [4096*4 .. )           maskslot (separate cache lines)
    // [65536 .. )            planes: 6 * pgs * 4B = 3 MB
    u32* popslot  = (u32*)d_ws;
    u32* maskslot = (u32*)((char*)d_ws + 16384);
    u32* planes   = (u32*)((char*)d_ws + 65536);

    k_count<<<gx, block, 0, stream>>>(flip, planes, popslot, npos, nvotes);
    k_apply<<<gx, block, 0, stream>>>(weights, planes, popslot, vote_p_max,
                                      n_votes_p, (float*)d_out, maskslot,
                                      npos, gx);
    k_ratio<<<1, block, 0, stream>>>(maskslot, (float*)d_out, npos, gx);
}